// Round 8
// baseline (349.263 us; speedup 1.0000x reference)
//
#include <hip/hip_runtime.h>
#include <hip/hip_bf16.h>
#include <stdint.h>

// CrossAttention on MI355X (gfx950), bf16 MFMA pipeline.
// R8: kernel-count 11 -> 4 (launch-overhead theory: non-flash time stuck at
//   ~240us across 3 different GEMM configs => ~8-10us/dispatch fixed cost).
//   prep = cvt + rmsnorm + 3x transpose_w (grid-sectioned);
//   qkv  = q-GEMM + kv-GEMM(+fragment-pack epilogue) fused (1536 blocks);
//   flash = R7 (no-spill, 256-reg budget) + 2-tile staging (half the barriers);
//   proj = GEMM + attn-mean constant write.

typedef __bf16 bf16_t;
typedef __bf16 bf16x8 __attribute__((ext_vector_type(8)));
typedef __bf16 bf16x4 __attribute__((ext_vector_type(4)));
typedef float  f32x4  __attribute__((ext_vector_type(4)));

#define BB 4
#define NN 2048
#define KC 2048
#define DD 1024
#define NH 16
#define HD 64
// 0.125 (=HEAD_DIM^-0.5) * log2(e): softmax done in exp2 domain
#define QSCALE 0.18033688011112042f
#define CLIP2  14.426950408889634f

__device__ __forceinline__ f32x4 mfma_16x16x32(bf16x8 a, bf16x8 b, f32x4 c) {
  return __builtin_amdgcn_mfma_f32_16x16x32_bf16(a, b, c, 0, 0, 0);
}

// async global->LDS, 16B per lane; LDS dest is wave-uniform base + lane*16.
__device__ __forceinline__ void gl_lds16(const bf16_t* g, bf16_t* l) {
  __builtin_amdgcn_global_load_lds(
      (const __attribute__((address_space(1))) void*)g,
      (__attribute__((address_space(3))) void*)l, 16, 0, 0);
}

// ---------------- prep: cvt(x) | rmsnorm(ctx) | 3x weight transpose ----------------
// grid 20480 x 256thr, sectioned by blockIdx.x:
//   [0,8192)      cvt x -> xb          (8M f32, float4/thread)
//   [8192,16384)  rmsnorm ctx -> ctxn  (one row/block)
//   [16384,17408) transpose q_w->qwT   (32x32 tiles, 32x32 grid)
//   [17408,19456) transpose kv_w->kvwT (64x32 grid)
//   [19456,20480) transpose proj_w->pwT
__device__ __forceinline__ void transpose_tile(const float* W, bf16_t* WT, int R, int C,
                                               int bx, int by, int tid, float (*tile)[33]) {
  int tx = tid & 31, ty = tid >> 5;
  int r0 = by * 32, c0 = bx * 32;
#pragma unroll
  for (int i = 0; i < 4; i++) tile[ty + 8 * i][tx] = W[(size_t)(r0 + ty + 8 * i) * C + c0 + tx];
  __syncthreads();
#pragma unroll
  for (int i = 0; i < 4; i++)
    WT[(size_t)(c0 + ty + 8 * i) * R + r0 + tx] = (bf16_t)tile[tx][ty + 8 * i];
}

__global__ __launch_bounds__(256) void prep(const float* __restrict__ x,
                                            const float* __restrict__ ctx,
                                            const float* __restrict__ q_w,
                                            const float* __restrict__ kv_w,
                                            const float* __restrict__ proj_w,
                                            bf16_t* __restrict__ xb, bf16_t* __restrict__ ctxn,
                                            bf16_t* __restrict__ qwT, bf16_t* __restrict__ kvwT,
                                            bf16_t* __restrict__ pwT) {
  __shared__ float tile[32][33];  // transpose sections; rmsnorm reuses first 4 floats
  int bid = blockIdx.x, tid = threadIdx.x;
  if (bid < 8192) {  // cvt
    int i = bid * 256 + tid;
    float4 v = ((const float4*)x)[i];
    bf16x4 o = {(bf16_t)v.x, (bf16_t)v.y, (bf16_t)v.z, (bf16_t)v.w};
    ((bf16x4*)xb)[i] = o;
  } else if (bid < 16384) {  // rmsnorm
    int row = bid - 8192;
    float4 v = ((const float4*)(ctx + (size_t)row * DD))[tid];
    float ss = v.x * v.x + v.y * v.y + v.z * v.z + v.w * v.w;
#pragma unroll
    for (int m = 1; m < 64; m <<= 1) ss += __shfl_xor(ss, m);
    if ((tid & 63) == 0) tile[0][tid >> 6] = ss;
    __syncthreads();
    float total = tile[0][0] + tile[0][1] + tile[0][2] + tile[0][3];
    float scale = rsqrtf(total * (1.0f / (float)DD) + 1e-6f);
    bf16x4 o = {(bf16_t)(v.x * scale), (bf16_t)(v.y * scale),
                (bf16_t)(v.z * scale), (bf16_t)(v.w * scale)};
    ((bf16x4*)(ctxn + (size_t)row * DD))[tid] = o;
  } else if (bid < 17408) {
    int idx = bid - 16384;
    transpose_tile(q_w, qwT, DD, DD, idx & 31, idx >> 5, tid, tile);
  } else if (bid < 19456) {
    int idx = bid - 17408;
    transpose_tile(kv_w, kvwT, DD, 2 * DD, idx & 63, idx >> 6, tid, tile);
  } else {
    int idx = bid - 19456;
    transpose_tile(proj_w, pwT, DD, DD, idx & 31, idx >> 5, tid, tile);
  }
}

// ---------------- GEMM core: C(MxN) = (A(MxK) @ Bt(NxK)^T + bias) * alpha ----------------
// MODE 0: bf16 Cout. MODE 1: f32 Cout. MODE 2: kv-pack epilogue.
// 1D swizzle: xcd=bid&7 owns row-panels [xcd*8,+8) x all (1<<gxlog) col-blocks.
template <int MODE>
__device__ __forceinline__ void gemm_core(const bf16_t* __restrict__ A,
                                          const bf16_t* __restrict__ Bt,
                                          const float* __restrict__ bias,
                                          void* __restrict__ Cout, bf16_t* __restrict__ kP,
                                          bf16_t* __restrict__ vP, int N, int Kd, float alpha,
                                          int gxlog, int bid, bf16_t* As, bf16_t* Bs) {
  int tid = threadIdx.x;
  int w = tid >> 6, lane = tid & 63;
  int quad = lane >> 4, l16 = lane & 15;
  int xcd = bid & 7, idx = bid >> 3;
  int row0 = (xcd * 8 + (idx >> gxlog)) * 128;
  int col0 = (idx & ((1 << gxlog) - 1)) * 128;
  int wm = (w >> 1) * 64, wn = (w & 1) * 64;

  f32x4 acc[4][4];
#pragma unroll
  for (int i = 0; i < 4; i++)
#pragma unroll
    for (int j = 0; j < 4; j++) acc[i][j] = (f32x4){0.f, 0.f, 0.f, 0.f};

  for (int kk = 0; kk < Kd; kk += 32) {
#pragma unroll
    for (int call = 0; call < 2; call++) {
      int c = w * 128 + call * 64 + lane;
      gl_lds16(&A[(size_t)(row0 + (c >> 2)) * Kd + kk + (c & 3) * 8],
               &As[(w * 128 + call * 64) * 8]);
      gl_lds16(&Bt[(size_t)(col0 + (c >> 2)) * Kd + kk + (c & 3) * 8],
               &Bs[(w * 128 + call * 64) * 8]);
    }
    __syncthreads();
    bf16x8 af[4], bfr[4];
#pragma unroll
    for (int mi = 0; mi < 4; mi++)
      af[mi] = *(const bf16x8*)&As[(wm + mi * 16 + l16) * 32 + quad * 8];
#pragma unroll
    for (int ni = 0; ni < 4; ni++)
      bfr[ni] = *(const bf16x8*)&Bs[(wn + ni * 16 + l16) * 32 + quad * 8];
#pragma unroll
    for (int mi = 0; mi < 4; mi++)
#pragma unroll
      for (int ni = 0; ni < 4; ni++) acc[mi][ni] = mfma_16x16x32(af[mi], bfr[ni], acc[mi][ni]);
    __syncthreads();
  }

  if (MODE == 2) {
    bool isK = (col0 < 1024);
    int cpart[4];
    float bv[4];
#pragma unroll
    for (int ni = 0; ni < 4; ni++) {
      int col = col0 + wn + ni * 16 + l16;
      bv[ni] = bias[col];
      int ch = isK ? col : (col - 1024);
      int h = ch >> 6, hd = ch & 63;
      if (isK)
        cpart[ni] = h * 131072 + (hd >> 5) * 512 + ((hd >> 3) & 3) * 8 + (hd & 7);
      else
        cpart[ni] = h * 131072 + (hd >> 4) * 512 + (hd & 15) * 32;
    }
#pragma unroll
    for (int mi = 0; mi < 4; mi++) {
#pragma unroll
      for (int r = 0; r < 4; r++) {
        int row = row0 + wm + mi * 16 + quad * 4 + r;
        int bb = row >> 11, kc = row & 2047;
        int t = kc >> 6, key = kc & 63;
        int rpart;
        if (isK) {
          rpart = bb * 2097152 + t * 4096 + (key >> 4) * 1024 + (key & 15) * 32;
        } else {
          int g = key >> 5, k2 = key & 31;
          rpart = bb * 2097152 + t * 4096 + g * 2048 + ((k2 >> 2) & 3) * 8 +
                  (((k2 >> 4) << 2) | (k2 & 3));
        }
        bf16_t* dst = isK ? kP : vP;
#pragma unroll
        for (int ni = 0; ni < 4; ni++)
          dst[(size_t)rpart + cpart[ni]] = (bf16_t)((acc[mi][ni][r] + bv[ni]) * alpha);
      }
    }
    return;
  }

#pragma unroll
  for (int ni = 0; ni < 4; ni++) {
    int col = col0 + wn + ni * 16 + l16;
    float bv = bias[ni == 0 ? col : col];  // keep simple
    bv = bias[col];
#pragma unroll
    for (int mi = 0; mi < 4; mi++) {
#pragma unroll
      for (int r = 0; r < 4; r++) {
        int row = row0 + wm + mi * 16 + quad * 4 + r;
        float v = (acc[mi][ni][r] + bv) * alpha;
        if (MODE == 1)
          ((float*)Cout)[(size_t)row * N + col] = v;
        else
          ((bf16_t*)Cout)[(size_t)row * N + col] = (bf16_t)v;
      }
    }
  }
}

// fused q-GEMM (blocks [0,512)) + kv-GEMM w/ pack epilogue (blocks [512,1536))
__global__ __launch_bounds__(256, 2) void gemm_qkv(const bf16_t* __restrict__ xb,
                                                   const bf16_t* __restrict__ qwT,
                                                   const float* __restrict__ q_b,
                                                   bf16_t* __restrict__ qbuf,
                                                   const bf16_t* __restrict__ ctxn,
                                                   const bf16_t* __restrict__ kvwT,
                                                   const float* __restrict__ kv_b,
                                                   bf16_t* __restrict__ kP,
                                                   bf16_t* __restrict__ vP) {
  __shared__ bf16_t As[128 * 32];
  __shared__ bf16_t Bs[128 * 32];
  int bid = blockIdx.x;
  if (bid < 512)
    gemm_core<0>(xb, qwT, q_b, qbuf, nullptr, nullptr, DD, DD, QSCALE, 3, bid, As, Bs);
  else
    gemm_core<2>(ctxn, kvwT, kv_b, nullptr, kP, vP, 2 * DD, DD, 1.0f, 4, bid - 512, As, Bs);
}

// proj GEMM (f32 out) + attn-mean scalar (softmax rows sum to 1 -> mean = 1/K)
__global__ __launch_bounds__(256, 2) void gemm_proj(const bf16_t* __restrict__ attn_out,
                                                    const bf16_t* __restrict__ pwT,
                                                    const float* __restrict__ proj_b,
                                                    float* __restrict__ out) {
  __shared__ bf16_t As[128 * 32];
  __shared__ bf16_t Bs[128 * 32];
  gemm_core<1>(attn_out, pwT, proj_b, out, nullptr, nullptr, DD, DD, 1.0f, 3, blockIdx.x, As, Bs);
  if (blockIdx.x == 0 && threadIdx.x == 0)
    out[(size_t)BB * NN * DD] = 1.0f / 2048.0f;
}

// ---------------- flash attention: query-split, qi=4, fragment-packed K/V ----------------
// 1024 blocks x 128 thr (2 waves, 256-reg budget); wave owns 64 q-rows.
// Per iter: stage TWO 64-key tiles (16 gl_lds16/wave, 32KB LDS) -> half the
// barriers of R7; conflict-free b128 frag reads; 64 K=32 MFMAs per tile
// (32 S^T + 32 PV via C-frag concat, k-label agreement).
__global__ __launch_bounds__(128, 2) void flash_attn(const bf16_t* __restrict__ qbuf,
                                                     const bf16_t* __restrict__ kP,
                                                     const bf16_t* __restrict__ vP,
                                                     bf16_t* __restrict__ attn_out) {
  __shared__ bf16_t Kp[2][4096];
  __shared__ bf16_t Vp[2][4096];
  __shared__ float rsinvS[2][64];

  int tid = threadIdx.x, w = tid >> 6, lane = tid & 63;
  int quad = lane >> 4, l16 = lane & 15;
  // 1024 blocks; xcd = bid&7 owns 8 whole (b,h): K+V 4MB = one XCD L2.
  int bid = blockIdx.x;
  int xcd = bid & 7, slot = bid >> 3;  // slot in [0,128)
  int bh = xcd * 8 + (slot >> 4);
  int qt = slot & 15;
  int b = bh >> 4, h = bh & 15;
  int n0 = qt * 128 + w * 64;  // wave-private 64 q-rows

  const bf16_t* kpb = kP + (size_t)bh * 32 * 4096;
  const bf16_t* vpb = vP + (size_t)bh * 32 * 4096;

  // Q-frags: B-operand of S^T. B[k=d=quad*8+j][n=query=qi*16+l16].
  bf16x8 qf[4][2];
#pragma unroll
  for (int qi = 0; qi < 4; qi++)
#pragma unroll
    for (int dc = 0; dc < 2; dc++)
      qf[qi][dc] = *(const bf16x8*)&qbuf[((size_t)b * NN + n0 + qi * 16 + l16) * DD + h * HD +
                                         dc * 32 + quad * 8];

  f32x4 o[4][4];  // [qi][hb]; C: row=quad*4+r = q-within-16, col=l16 = hd-within-16
#pragma unroll
  for (int qi = 0; qi < 4; qi++)
#pragma unroll
    for (int hb = 0; hb < 4; hb++) o[qi][hb] = (f32x4){0.f, 0.f, 0.f, 0.f};
  float rs[4] = {0.f, 0.f, 0.f, 0.f};

  for (int t = 0; t < KC / 64; t += 2) {
    __syncthreads();  // prev iter's frag reads done
#pragma unroll
    for (int u = 0; u < 2; u++) {
#pragma unroll
      for (int i = 0; i < 4; i++) {  // each wave stages half of K and half of V
        int j = w * 4 + i;
        gl_lds16(&kpb[(size_t)(t + u) * 4096 + j * 512 + lane * 8], &Kp[u][j * 512]);
        gl_lds16(&vpb[(size_t)(t + u) * 4096 + j * 512 + lane * 8], &Vp[u][j * 512]);
      }
    }
    __syncthreads();  // drains vmcnt (gl_lds16 DMA)

#pragma unroll
    for (int u = 0; u < 2; u++) {
      // K frags: A[m=key=l16][k=d=quad*8+j] per (ki,dc); conflict-free b128.
      bf16x8 kf[4][2];
#pragma unroll
      for (int ki = 0; ki < 4; ki++)
#pragma unroll
        for (int dc = 0; dc < 2; dc++)
          kf[ki][dc] = *(const bf16x8*)&Kp[u][(ki * 2 + dc) * 512 + (l16 * 4 + quad) * 8];
      // V frags: B[k-slot(quad,j) -> key g*32+quad*4+(j&3)+(j>>2)*16][n=hd].
      bf16x8 vb[2][4];
#pragma unroll
      for (int g = 0; g < 2; g++)
#pragma unroll
        for (int hb = 0; hb < 4; hb++)
          vb[g][hb] = *(const bf16x8*)&Vp[u][(g * 4 + hb) * 512 + (l16 * 4 + quad) * 8];

#pragma unroll
      for (int qi = 0; qi < 4; qi++) {
#pragma unroll
        for (int g = 0; g < 2; g++) {
          union { bf16x8 v8; bf16x4 h[2]; } pf;
#pragma unroll
          for (int sub = 0; sub < 2; sub++) {
            f32x4 s = (f32x4){0.f, 0.f, 0.f, 0.f};
            s = mfma_16x16x32(kf[g * 2 + sub][0], qf[qi][0], s);
            s = mfma_16x16x32(kf[g * 2 + sub][1], qf[qi][1], s);
            bf16x4 pb;
#pragma unroll
            for (int r = 0; r < 4; r++) {
              float pv = __builtin_amdgcn_exp2f(__builtin_amdgcn_fmed3f(s[r], -CLIP2, CLIP2));
              rs[qi] += pv;
              pb[r] = (bf16_t)pv;
            }
            pf.h[sub] = pb;
          }
#pragma unroll
          for (int hb = 0; hb < 4; hb++)
            o[qi][hb] = mfma_16x16x32(pf.v8, vb[g][hb], o[qi][hb]);
        }
      }
    }
  }

  // full row-sums (sum quads; per-wave LDS broadcast, no barrier needed)
#pragma unroll
  for (int qi = 0; qi < 4; qi++) {
    float v = rs[qi];
    v += __shfl_xor(v, 16);
    v += __shfl_xor(v, 32);
    if (quad == 0) rsinvS[w][qi * 16 + l16] = 1.0f / v;
  }
#pragma unroll
  for (int qi = 0; qi < 4; qi++) {
    f32x4 ri = *(const f32x4*)&rsinvS[w][qi * 16 + quad * 4];
#pragma unroll
    for (int hb = 0; hb < 4; hb++) {
#pragma unroll
      for (int r = 0; r < 4; r++) {
        int row = n0 + qi * 16 + quad * 4 + r;
        int col = h * HD + hb * 16 + l16;
        attn_out[((size_t)b * NN + row) * DD + col] = (bf16_t)(o[qi][hb][r] * ri[r]);
      }
    }
  }
}

// ---------------- launch ----------------
extern "C" void kernel_launch(void* const* d_in, const int* in_sizes, int n_in, void* d_out,
                              int out_size, void* d_ws, size_t ws_size, hipStream_t stream) {
  const float* x      = (const float*)d_in[0];
  const float* ctx    = (const float*)d_in[1];
  const float* q_w    = (const float*)d_in[2];
  const float* q_b    = (const float*)d_in[3];
  const float* kv_w   = (const float*)d_in[4];
  const float* kv_b   = (const float*)d_in[5];
  const float* proj_w = (const float*)d_in[6];
  const float* proj_b = (const float*)d_in[7];
  float* out = (float*)d_out;
  char* ws = (char*)d_ws;

  bf16_t* xb    = (bf16_t*)(ws + 0);          // 16 MB, dead after q GEMM
  bf16_t* ctxn  = (bf16_t*)(ws + 16777216);   // 16 MB, dead after kv GEMM
  bf16_t* qwT   = (bf16_t*)(ws + 33554432);   // 2 MB
  bf16_t* kvwT  = (bf16_t*)(ws + 35651584);   // 4 MB
  bf16_t* pwT   = (bf16_t*)(ws + 39845888);   // 2 MB
  bf16_t* qbuf  = (bf16_t*)(ws + 41943040);   // 16 MB
  bf16_t* kP    = (bf16_t*)(ws + 58720256);   // 16 MB, fragment-packed K
  bf16_t* vP    = (bf16_t*)(ws + 75497472);   // 16 MB, fragment-packed V
  bf16_t* attn_out = xb;                      // alias: written after xb consumed

  prep<<<20480, 256, 0, stream>>>(x, ctx, q_w, kv_w, proj_w, xb, ctxn, qwT, kvwT, pwT);
  gemm_qkv<<<1536, 256, 0, stream>>>(xb, qwT, q_b, qbuf, ctxn, kvwT, kv_b, kP, vP);
  flash_attn<<<1024, 128, 0, stream>>>(qbuf, kP, vP, attn_out);
  gemm_proj<<<512, 256, 0, stream>>>(attn_out, pwT, proj_b, out);
}

// Round 9
// 321.379 us; speedup vs baseline: 1.0868x; 1.0868x over previous
//
#include <hip/hip_runtime.h>
#include <hip/hip_bf16.h>
#include <stdint.h>

// CrossAttention on MI355X (gfx950), bf16 MFMA pipeline.
// R9: (1) flash reverted to R7's exact single-tile loop (R8's 2-tile unroll
//   hoisted both tiles' frag reads -> +64 VGPR -> 137MB spill; rule: one
//   tile's fragments in flight max). (2) GEMM BK 32->64: two half-tiles of
//   the m97 layout per barrier pair (32KB LDS, still 2 blk/CU) -> half the
//   barriers, 2x MFMA per drain; K=1024 loops were drain-dominated.

typedef __bf16 bf16_t;
typedef __bf16 bf16x8 __attribute__((ext_vector_type(8)));
typedef __bf16 bf16x4 __attribute__((ext_vector_type(4)));
typedef float  f32x4  __attribute__((ext_vector_type(4)));

#define BB 4
#define NN 2048
#define KC 2048
#define DD 1024
#define NH 16
#define HD 64
// 0.125 (=HEAD_DIM^-0.5) * log2(e): softmax done in exp2 domain
#define QSCALE 0.18033688011112042f
#define CLIP2  14.426950408889634f

__device__ __forceinline__ f32x4 mfma_16x16x32(bf16x8 a, bf16x8 b, f32x4 c) {
  return __builtin_amdgcn_mfma_f32_16x16x32_bf16(a, b, c, 0, 0, 0);
}

// async global->LDS, 16B per lane; LDS dest is wave-uniform base + lane*16.
__device__ __forceinline__ void gl_lds16(const bf16_t* g, bf16_t* l) {
  __builtin_amdgcn_global_load_lds(
      (const __attribute__((address_space(1))) void*)g,
      (__attribute__((address_space(3))) void*)l, 16, 0, 0);
}

// ---------------- prep: cvt(x) | rmsnorm(ctx) | 3x weight transpose ----------------
__device__ __forceinline__ void transpose_tile(const float* W, bf16_t* WT, int R, int C,
                                               int bx, int by, int tid, float (*tile)[33]) {
  int tx = tid & 31, ty = tid >> 5;
  int r0 = by * 32, c0 = bx * 32;
#pragma unroll
  for (int i = 0; i < 4; i++) tile[ty + 8 * i][tx] = W[(size_t)(r0 + ty + 8 * i) * C + c0 + tx];
  __syncthreads();
#pragma unroll
  for (int i = 0; i < 4; i++)
    WT[(size_t)(c0 + ty + 8 * i) * R + r0 + tx] = (bf16_t)tile[tx][ty + 8 * i];
}

__global__ __launch_bounds__(256) void prep(const float* __restrict__ x,
                                            const float* __restrict__ ctx,
                                            const float* __restrict__ q_w,
                                            const float* __restrict__ kv_w,
                                            const float* __restrict__ proj_w,
                                            bf16_t* __restrict__ xb, bf16_t* __restrict__ ctxn,
                                            bf16_t* __restrict__ qwT, bf16_t* __restrict__ kvwT,
                                            bf16_t* __restrict__ pwT) {
  __shared__ float tile[32][33];
  int bid = blockIdx.x, tid = threadIdx.x;
  if (bid < 8192) {  // cvt x -> bf16
    int i = bid * 256 + tid;
    float4 v = ((const float4*)x)[i];
    bf16x4 o = {(bf16_t)v.x, (bf16_t)v.y, (bf16_t)v.z, (bf16_t)v.w};
    ((bf16x4*)xb)[i] = o;
  } else if (bid < 16384) {  // rmsnorm ctx
    int row = bid - 8192;
    float4 v = ((const float4*)(ctx + (size_t)row * DD))[tid];
    float ss = v.x * v.x + v.y * v.y + v.z * v.z + v.w * v.w;
#pragma unroll
    for (int m = 1; m < 64; m <<= 1) ss += __shfl_xor(ss, m);
    if ((tid & 63) == 0) tile[0][tid >> 6] = ss;
    __syncthreads();
    float total = tile[0][0] + tile[0][1] + tile[0][2] + tile[0][3];
    float scale = rsqrtf(total * (1.0f / (float)DD) + 1e-6f);
    bf16x4 o = {(bf16_t)(v.x * scale), (bf16_t)(v.y * scale),
                (bf16_t)(v.z * scale), (bf16_t)(v.w * scale)};
    ((bf16x4*)(ctxn + (size_t)row * DD))[tid] = o;
  } else if (bid < 17408) {
    int idx = bid - 16384;
    transpose_tile(q_w, qwT, DD, DD, idx & 31, idx >> 5, tid, tile);
  } else if (bid < 19456) {
    int idx = bid - 17408;
    transpose_tile(kv_w, kvwT, DD, 2 * DD, idx & 63, idx >> 6, tid, tile);
  } else {
    int idx = bid - 19456;
    transpose_tile(proj_w, pwT, DD, DD, idx & 31, idx >> 5, tid, tile);
  }
}

// ---------------- GEMM core, BK=64: C(MxN) = (A(MxK) @ Bt(NxK)^T + bias) * alpha ----
// Two m97-layout half-tiles (32-wide) per barrier pair; 32 MFMA/wave/iter.
// MODE 0: bf16 Cout. MODE 1: f32 Cout. MODE 2: kv-pack epilogue.
// 1D swizzle: xcd=bid&7 owns row-panels [xcd*8,+8) x all (1<<gxlog) col-blocks.
template <int MODE>
__device__ __forceinline__ void gemm_core(const bf16_t* __restrict__ A,
                                          const bf16_t* __restrict__ Bt,
                                          const float* __restrict__ bias,
                                          void* __restrict__ Cout, bf16_t* __restrict__ kP,
                                          bf16_t* __restrict__ vP, int N, int Kd, float alpha,
                                          int gxlog, int bid, bf16_t* As, bf16_t* Bs) {
  int tid = threadIdx.x;
  int w = tid >> 6, lane = tid & 63;
  int quad = lane >> 4, l16 = lane & 15;
  int xcd = bid & 7, idx = bid >> 3;
  int row0 = (xcd * 8 + (idx >> gxlog)) * 128;
  int col0 = (idx & ((1 << gxlog) - 1)) * 128;
  int wm = (w >> 1) * 64, wn = (w & 1) * 64;

  f32x4 acc[4][4];
#pragma unroll
  for (int i = 0; i < 4; i++)
#pragma unroll
    for (int j = 0; j < 4; j++) acc[i][j] = (f32x4){0.f, 0.f, 0.f, 0.f};

  for (int kk = 0; kk < Kd; kk += 64) {
#pragma unroll
    for (int half = 0; half < 2; half++) {
#pragma unroll
      for (int call = 0; call < 2; call++) {
        int c = w * 128 + call * 64 + lane;
        gl_lds16(&A[(size_t)(row0 + (c >> 2)) * Kd + kk + half * 32 + (c & 3) * 8],
                 &As[half * 4096 + (w * 128 + call * 64) * 8]);
        gl_lds16(&Bt[(size_t)(col0 + (c >> 2)) * Kd + kk + half * 32 + (c & 3) * 8],
                 &Bs[half * 4096 + (w * 128 + call * 64) * 8]);
      }
    }
    __syncthreads();
#pragma unroll
    for (int half = 0; half < 2; half++) {
      bf16x8 af[4], bfr[4];
#pragma unroll
      for (int mi = 0; mi < 4; mi++)
        af[mi] = *(const bf16x8*)&As[half * 4096 + (wm + mi * 16 + l16) * 32 + quad * 8];
#pragma unroll
      for (int ni = 0; ni < 4; ni++)
        bfr[ni] = *(const bf16x8*)&Bs[half * 4096 + (wn + ni * 16 + l16) * 32 + quad * 8];
#pragma unroll
      for (int mi = 0; mi < 4; mi++)
#pragma unroll
        for (int ni = 0; ni < 4; ni++)
          acc[mi][ni] = mfma_16x16x32(af[mi], bfr[ni], acc[mi][ni]);
    }
    __syncthreads();
  }

  if (MODE == 2) {
    bool isK = (col0 < 1024);
    int cpart[4];
    float bv[4];
#pragma unroll
    for (int ni = 0; ni < 4; ni++) {
      int col = col0 + wn + ni * 16 + l16;
      bv[ni] = bias[col];
      int ch = isK ? col : (col - 1024);
      int h = ch >> 6, hd = ch & 63;
      if (isK)
        cpart[ni] = h * 131072 + (hd >> 5) * 512 + ((hd >> 3) & 3) * 8 + (hd & 7);
      else
        cpart[ni] = h * 131072 + (hd >> 4) * 512 + (hd & 15) * 32;
    }
#pragma unroll
    for (int mi = 0; mi < 4; mi++) {
#pragma unroll
      for (int r = 0; r < 4; r++) {
        int row = row0 + wm + mi * 16 + quad * 4 + r;
        int bb = row >> 11, kc = row & 2047;
        int t = kc >> 6, key = kc & 63;
        int rpart;
        if (isK) {
          rpart = bb * 2097152 + t * 4096 + (key >> 4) * 1024 + (key & 15) * 32;
        } else {
          int g = key >> 5, k2 = key & 31;
          rpart = bb * 2097152 + t * 4096 + g * 2048 + ((k2 >> 2) & 3) * 8 +
                  (((k2 >> 4) << 2) | (k2 & 3));
        }
        bf16_t* dst = isK ? kP : vP;
#pragma unroll
        for (int ni = 0; ni < 4; ni++)
          dst[(size_t)rpart + cpart[ni]] = (bf16_t)((acc[mi][ni][r] + bv[ni]) * alpha);
      }
    }
    return;
  }

#pragma unroll
  for (int ni = 0; ni < 4; ni++) {
    int col = col0 + wn + ni * 16 + l16;
    float bv = bias[col];
#pragma unroll
    for (int mi = 0; mi < 4; mi++) {
#pragma unroll
      for (int r = 0; r < 4; r++) {
        int row = row0 + wm + mi * 16 + quad * 4 + r;
        float v = (acc[mi][ni][r] + bv) * alpha;
        if (MODE == 1)
          ((float*)Cout)[(size_t)row * N + col] = v;
        else
          ((bf16_t*)Cout)[(size_t)row * N + col] = (bf16_t)v;
      }
    }
  }
}

// fused q-GEMM (blocks [0,512)) + kv-GEMM w/ pack epilogue (blocks [512,1536))
__global__ __launch_bounds__(256, 2) void gemm_qkv(const bf16_t* __restrict__ xb,
                                                   const bf16_t* __restrict__ qwT,
                                                   const float* __restrict__ q_b,
                                                   bf16_t* __restrict__ qbuf,
                                                   const bf16_t* __restrict__ ctxn,
                                                   const bf16_t* __restrict__ kvwT,
                                                   const float* __restrict__ kv_b,
                                                   bf16_t* __restrict__ kP,
                                                   bf16_t* __restrict__ vP) {
  __shared__ bf16_t As[128 * 64];
  __shared__ bf16_t Bs[128 * 64];
  int bid = blockIdx.x;
  if (bid < 512)
    gemm_core<0>(xb, qwT, q_b, qbuf, nullptr, nullptr, DD, DD, QSCALE, 3, bid, As, Bs);
  else
    gemm_core<2>(ctxn, kvwT, kv_b, nullptr, kP, vP, 2 * DD, DD, 1.0f, 4, bid - 512, As, Bs);
}

// proj GEMM (f32 out) + attn-mean scalar (softmax rows sum to 1 -> mean = 1/K)
__global__ __launch_bounds__(256, 2) void gemm_proj(const bf16_t* __restrict__ attn_out,
                                                    const bf16_t* __restrict__ pwT,
                                                    const float* __restrict__ proj_b,
                                                    float* __restrict__ out) {
  __shared__ bf16_t As[128 * 64];
  __shared__ bf16_t Bs[128 * 64];
  gemm_core<1>(attn_out, pwT, proj_b, out, nullptr, nullptr, DD, DD, 1.0f, 3, blockIdx.x, As, Bs);
  if (blockIdx.x == 0 && threadIdx.x == 0)
    out[(size_t)BB * NN * DD] = 1.0f / 2048.0f;
}

// ---------------- flash attention: query-split, qi=4, fragment-packed K/V ----------------
// R7-verified loop (91us, no spill): 1024 blocks x 128 thr (2 waves, 256-reg
// budget); wave owns 64 q-rows. Per 64-key tile: stage kP/vP (8KB each) via
// linear gl_lds16; conflict-free b128 frag reads; 64 K=32 MFMAs per wave
// (32 S^T + 32 PV via C-frag concat, k-label agreement). ONE tile's frags
// in flight max (2-tile unroll spills — R8).
__global__ __launch_bounds__(128, 2) void flash_attn(const bf16_t* __restrict__ qbuf,
                                                     const bf16_t* __restrict__ kP,
                                                     const bf16_t* __restrict__ vP,
                                                     bf16_t* __restrict__ attn_out) {
  __shared__ bf16_t Kp[4096];
  __shared__ bf16_t Vp[4096];
  __shared__ float rsinvS[2][64];

  int tid = threadIdx.x, w = tid >> 6, lane = tid & 63;
  int quad = lane >> 4, l16 = lane & 15;
  // 1024 blocks; xcd = bid&7 owns 8 whole (b,h): K+V 4MB = one XCD L2.
  int bid = blockIdx.x;
  int xcd = bid & 7, slot = bid >> 3;  // slot in [0,128)
  int bh = xcd * 8 + (slot >> 4);
  int qt = slot & 15;
  int b = bh >> 4, h = bh & 15;
  int n0 = qt * 128 + w * 64;  // wave-private 64 q-rows

  const bf16_t* kpb = kP + (size_t)bh * 32 * 4096;
  const bf16_t* vpb = vP + (size_t)bh * 32 * 4096;

  // Q-frags: B-operand of S^T. B[k=d=quad*8+j][n=query=qi*16+l16].
  bf16x8 qf[4][2];
#pragma unroll
  for (int qi = 0; qi < 4; qi++)
#pragma unroll
    for (int dc = 0; dc < 2; dc++)
      qf[qi][dc] = *(const bf16x8*)&qbuf[((size_t)b * NN + n0 + qi * 16 + l16) * DD + h * HD +
                                         dc * 32 + quad * 8];

  f32x4 o[4][4];  // [qi][hb]; C: row=quad*4+r = q-within-16, col=l16 = hd-within-16
#pragma unroll
  for (int qi = 0; qi < 4; qi++)
#pragma unroll
    for (int hb = 0; hb < 4; hb++) o[qi][hb] = (f32x4){0.f, 0.f, 0.f, 0.f};
  float rs[4] = {0.f, 0.f, 0.f, 0.f};

  for (int t = 0; t < KC / 64; t++) {
    __syncthreads();  // prev iter's frag reads done
#pragma unroll
    for (int i = 0; i < 4; i++) {  // each wave stages half of K and half of V
      int j = w * 4 + i;
      gl_lds16(&kpb[(size_t)t * 4096 + j * 512 + lane * 8], &Kp[j * 512]);
      gl_lds16(&vpb[(size_t)t * 4096 + j * 512 + lane * 8], &Vp[j * 512]);
    }
    __syncthreads();  // drains vmcnt (gl_lds16 DMA)

    // K frags: A[m=key=l16][k=d=quad*8+j] per (ki,dc); conflict-free b128.
    bf16x8 kf[4][2];
#pragma unroll
    for (int ki = 0; ki < 4; ki++)
#pragma unroll
      for (int dc = 0; dc < 2; dc++)
        kf[ki][dc] = *(const bf16x8*)&Kp[(ki * 2 + dc) * 512 + (l16 * 4 + quad) * 8];
    // V frags: B[k-slot(quad,j) -> key g*32+quad*4+(j&3)+(j>>2)*16][n=hd].
    bf16x8 vb[2][4];
#pragma unroll
    for (int g = 0; g < 2; g++)
#pragma unroll
      for (int hb = 0; hb < 4; hb++)
        vb[g][hb] = *(const bf16x8*)&Vp[(g * 4 + hb) * 512 + (l16 * 4 + quad) * 8];

#pragma unroll
    for (int qi = 0; qi < 4; qi++) {
#pragma unroll
      for (int g = 0; g < 2; g++) {
        union { bf16x8 v8; bf16x4 h[2]; } pf;
#pragma unroll
        for (int sub = 0; sub < 2; sub++) {
          f32x4 s = (f32x4){0.f, 0.f, 0.f, 0.f};
          s = mfma_16x16x32(kf[g * 2 + sub][0], qf[qi][0], s);
          s = mfma_16x16x32(kf[g * 2 + sub][1], qf[qi][1], s);
          bf16x4 pb;
#pragma unroll
          for (int r = 0; r < 4; r++) {
            float pv = __builtin_amdgcn_exp2f(__builtin_amdgcn_fmed3f(s[r], -CLIP2, CLIP2));
            rs[qi] += pv;
            pb[r] = (bf16_t)pv;
          }
          pf.h[sub] = pb;
        }
#pragma unroll
        for (int hb = 0; hb < 4; hb++)
          o[qi][hb] = mfma_16x16x32(pf.v8, vb[g][hb], o[qi][hb]);
      }
    }
  }

  // full row-sums (sum quads; per-wave LDS broadcast, no barrier needed)
#pragma unroll
  for (int qi = 0; qi < 4; qi++) {
    float v = rs[qi];
    v += __shfl_xor(v, 16);
    v += __shfl_xor(v, 32);
    if (quad == 0) rsinvS[w][qi * 16 + l16] = 1.0f / v;
  }
#pragma unroll
  for (int qi = 0; qi < 4; qi++) {
    f32x4 ri = *(const f32x4*)&rsinvS[w][qi * 16 + quad * 4];
#pragma unroll
    for (int hb = 0; hb < 4; hb++) {
#pragma unroll
      for (int r = 0; r < 4; r++) {
        int row = n0 + qi * 16 + quad * 4 + r;
        int col = h * HD + hb * 16 + l16;
        attn_out[((size_t)b * NN + row) * DD + col] = (bf16_t)(o[qi][hb][r] * ri[r]);
      }
    }
  }
}

// ---------------- launch ----------------
extern "C" void kernel_launch(void* const* d_in, const int* in_sizes, int n_in, void* d_out,
                              int out_size, void* d_ws, size_t ws_size, hipStream_t stream) {
  const float* x      = (const float*)d_in[0];
  const float* ctx    = (const float*)d_in[1];
  const float* q_w    = (const float*)d_in[2];
  const float* q_b    = (const float*)d_in[3];
  const float* kv_w   = (const float*)d_in[4];
  const float* kv_b   = (const float*)d_in[5];
  const float* proj_w = (const float*)d_in[6];
  const float* proj_b = (const float*)d_in[7];
  float* out = (float*)d_out;
  char* ws = (char*)d_ws;

  bf16_t* xb    = (bf16_t*)(ws + 0);          // 16 MB, dead after q GEMM
  bf16_t* ctxn  = (bf16_t*)(ws + 16777216);   // 16 MB, dead after kv GEMM
  bf16_t* qwT   = (bf16_t*)(ws + 33554432);   // 2 MB
  bf16_t* kvwT  = (bf16_t*)(ws + 35651584);   // 4 MB
  bf16_t* pwT   = (bf16_t*)(ws + 39845888);   // 2 MB
  bf16_t* qbuf  = (bf16_t*)(ws + 41943040);   // 16 MB
  bf16_t* kP    = (bf16_t*)(ws + 58720256);   // 16 MB, fragment-packed K
  bf16_t* vP    = (bf16_t*)(ws + 75497472);   // 16 MB, fragment-packed V
  bf16_t* attn_out = xb;                      // alias: written after xb consumed

  prep<<<20480, 256, 0, stream>>>(x, ctx, q_w, kv_w, proj_w, xb, ctxn, qwT, kvwT, pwT);
  gemm_qkv<<<1536, 256, 0, stream>>>(xb, qwT, q_b, qbuf, ctxn, kvwT, kv_b, kP, vP);
  flash_attn<<<1024, 128, 0, stream>>>(qbuf, kP, vP, attn_out);
  gemm_proj<<<512, 256, 0, stream>>>(attn_out, pwT, proj_b, out);
}